// Round 6
// baseline (69.489 us; speedup 1.0000x reference)
//
#include <hip/hip_runtime.h>

typedef float v2f __attribute__((ext_vector_type(2)));

#define NN 4096
#define TTOT 8192

constexpr int ROWS   = 32;    // n-rows per block
constexpr int TCOLS  = 256;   // t per tile
constexpr int UNITS  = 64;    // float4 units per row per tile
constexpr int S      = 32;    // t per compute thread
constexpr int HALO   = 4;     // 4 kernel-2 layers -> cone of 4
constexpr int CTILES = 8;     // tiles per block (iterated)
constexpr int CHUNK  = TCOLS * CTILES;   // 2048 t per block

__device__ __forceinline__ float fexp2(float x) {
#if __has_builtin(__builtin_amdgcn_exp2f)
    return __builtin_amdgcn_exp2f(x);
#else
    return exp2f(x);
#endif
}
__device__ __forceinline__ float frcp(float x) {
#if __has_builtin(__builtin_amdgcn_rcpf)
    return __builtin_amdgcn_rcpf(x);
#else
    return 1.0f / x;
#endif
}
__device__ __forceinline__ v2f splat(float x) { v2f r = {x, x}; return r; }

#if __has_builtin(__builtin_amdgcn_global_load_lds)
#define HAVE_GLD 1
typedef const __attribute__((address_space(1))) void g_void;
typedef __attribute__((address_space(3))) void l_void;
#endif

__global__ __launch_bounds__(256, 2) void gdcn_kernel(
    const float* __restrict__ x,
    const float* __restrict__ start_w,
    const float* __restrict__ start_b,
    const float* __restrict__ filter_w,
    const float* __restrict__ filter_b,
    const float* __restrict__ gate_w,
    const float* __restrict__ gate_b,
    float* __restrict__ out)
{
    __shared__ float4 B[2][ROWS * UNITS];   // 2 x 32 KiB

    const int tid  = threadIdx.x;
    const int nb   = blockIdx.x & 127;      // 128 n-blocks
    const int ch   = blockIdx.x >> 7;       // 4 t-chunks
    const int n0   = nb * ROWS;
    const int t0   = ch * CHUNK;

    const int w    = tid >> 6;              // wave 0..3
    const int lane = tid & 63;
    const int cr   = tid & 31;              // compute row
    const int cj   = tid >> 5;              // 32-t segment 0..7
    const int sx   = cr & 7;                // swizzle key

    // ---- coefficients (uniform) ----
    constexpr float LOG2E = 1.4426950408889634f;
    const float sw = start_w[0], sb = start_b[0];
    float ff0[4], ff1[4], ffb[4], gg0[4], gg1[4], ggb[4];
    #pragma unroll
    for (int i = 0; i < 4; ++i) {
        ff0[i] = filter_w[2*i]   * (2.0f * LOG2E);
        ff1[i] = filter_w[2*i+1] * (2.0f * LOG2E);
        ffb[i] = filter_b[i]     * (2.0f * LOG2E);
        gg0[i] = -gate_w[2*i]    * LOG2E;
        gg1[i] = -gate_w[2*i+1]  * LOG2E;
        ggb[i] = -gate_b[i]      * LOG2E;
    }

    // stage tile -> LDS buffer b. Wave-instruction = one full row (1 KiB
    // contiguous). Source pre-swizzled (lane^(r&7)) so linear LDS dest
    // yields conflict-free reads (both-sides swizzle rule).
    auto stage = [&](int tile, int b) {
        const float* base = x + (size_t)n0 * TTOT + (t0 + tile * TCOLS);
        #pragma unroll
        for (int i = 0; i < 8; ++i) {
            const int r = i * 4 + w;                    // wave-uniform row
            const float* src = base + (size_t)r * TTOT + ((lane ^ (r & 7)) << 2);
#ifdef HAVE_GLD
            __builtin_amdgcn_global_load_lds((g_void*)src,
                                             (l_void*)&B[b][r * UNITS],
                                             16, 0, 0);
#else
            B[b][r * UNITS + lane] = *reinterpret_cast<const float4*>(src);
#endif
        }
    };

    // halo for iteration `it` (first 4 t after its tile), cj==7 threads only
    auto load_halo = [&](int it) -> float4 {
        float4 h = {0.f, 0.f, 0.f, 0.f};
        const int th = t0 + (it + 1) * TCOLS;
        if (cj == 7 && th < TTOT)
            h = *reinterpret_cast<const float4*>(x + (size_t)(n0 + cr) * TTOT + th);
        return h;
    };

    // ---- prologue ----
    stage(0, 0);
    float4 hreg = load_halo(0);
    __syncthreads();                         // drains the staging loads

    #pragma unroll 2
    for (int it = 0; it < CTILES; ++it) {
        const int cur = it & 1;
        const int tbase = t0 + it * TCOLS + cj * S;
        const float4* buf = B[cur];
        const int rb = cr * UNITS + cj * 8;

        // ---- LDS -> registers (swizzled reads, even bank spread) ----
        float v[S + HALO];
        #pragma unroll
        for (int q = 0; q < 8; ++q) {
            float4 f4 = buf[rb + (q ^ sx)];
            v[4*q+0] = f4.x; v[4*q+1] = f4.y; v[4*q+2] = f4.z; v[4*q+3] = f4.w;
        }
        {
            float4 f4;
            if (cj < 7) f4 = buf[rb + 8 + sx];   // next segment's first unit
            else        f4 = hreg;               // register halo
            v[32] = f4.x; v[33] = f4.y; v[34] = f4.z; v[35] = f4.w;
        }

        // ---- issue next tile's async loads (overlap with compute) ----
        if (it + 1 < CTILES) {
            stage(it + 1, cur ^ 1);
            hreg = load_halo(it + 1);
        }

        // ---- math ----
        #pragma unroll
        for (int s = 0; s < S + HALO; ++s) v[s] = fmaf(v[s], sw, sb);
        const bool edge = (tbase + S + HALO > TTOT);   // ch==3, it==7, cj==7
        if (edge) { v[32] = v[33] = v[34] = v[35] = 0.f; }

        #pragma unroll
        for (int i = 0; i < 4; ++i) {
            const int len = S + HALO - 1 - i;       // 35,34,33,32
            #pragma unroll
            for (int s = 0; s + 1 < len; s += 2) {
                v2f a = { v[s],   v[s+1] };
                v2f b = { v[s+1], v[s+2] };
                v2f tf = a * splat(ff0[i]) + b * splat(ff1[i]) + splat(ffb[i]);
                v2f tg = a * splat(gg0[i]) + b * splat(gg1[i]) + splat(ggb[i]);
                if (i == 0) {   // layer-0 input unbounded: keep den in range
                    tf.x = fminf(tf.x, 60.0f); tf.y = fminf(tf.y, 60.0f);
                    tg.x = fminf(tg.x, 60.0f); tg.y = fminf(tg.y, 60.0f);
                }
                v2f ef = { fexp2(tf.x), fexp2(tf.y) };
                v2f eg = { fexp2(tg.x), fexp2(tg.y) };
                v2f num = ef - splat(1.0f);
                v2f den = (ef + splat(1.0f)) * (eg + splat(1.0f));
                v2f r   = { frcp(den.x), frcp(den.y) };
                v2f res = num * r;
                v[s] = res.x; v[s+1] = res.y;
            }
            if (len & 1) {
                const int s = len - 1;
                float a = v[s], b = v[s + 1];
                float tf = fmaf(a, ff0[i], fmaf(b, ff1[i], ffb[i]));
                float tg = fmaf(a, gg0[i], fmaf(b, gg1[i], ggb[i]));
                if (i == 0) { tf = fminf(tf, 60.0f); tg = fminf(tg, 60.0f); }
                float ef = fexp2(tf), eg = fexp2(tg);
                v[s] = (ef - 1.0f) * frcp((ef + 1.0f) * (eg + 1.0f));
            }
            if (edge) { v[32] = v[33] = v[34] = v[35] = 0.f; }
        }

        // ---- store: out[t][n]; 32 contiguous n per half-wave = 128B runs ----
        float* op = out + (size_t)tbase * NN + n0 + cr;
        #pragma unroll
        for (int s = 0; s < S; ++s)
            op[(size_t)s * NN] = v[s];

        __syncthreads();   // next tile staged + this buffer free to reuse
    }
}

extern "C" void kernel_launch(void* const* d_in, const int* in_sizes, int n_in,
                              void* d_out, int out_size, void* d_ws, size_t ws_size,
                              hipStream_t stream) {
    const float* x  = (const float*)d_in[0];
    const float* sw = (const float*)d_in[1];
    const float* sb = (const float*)d_in[2];
    const float* fw = (const float*)d_in[3];
    const float* fb = (const float*)d_in[4];
    const float* gw = (const float*)d_in[5];
    const float* gb = (const float*)d_in[6];
    float* out = (float*)d_out;

    dim3 grid((NN / ROWS) * (TTOT / CHUNK));   // 128 * 4 = 512 blocks (2/CU)
    gdcn_kernel<<<grid, 256, 0, stream>>>(x, sw, sb, fw, fb, gw, gb, out);
}